// Round 1
// baseline (66.326 us; speedup 1.0000x reference)
//
#include <hip/hip_runtime.h>

#define BB   32
#define CH   3
#define HH   512
#define WW   512
#define SH   364
#define SW   280
#define RAD  15
#define NK   96
#define HMN  (SH*SW)          // 101920
#define OMN  (HH*WW)          // 262144

// ---------------- zero the heatmap ----------------
__global__ void k_zero(float* __restrict__ p, int n) {
    int i = blockIdx.x * blockDim.x + threadIdx.x;
    if (i < n) p[i] = 0.0f;
}

// ---------------- scatter keypoints ----------------
__global__ void k_scatter(const float* __restrict__ lm, float* __restrict__ hm) {
    int t = blockIdx.x * blockDim.x + threadIdx.x;
    if (t >= BB * NK) return;
    int b = t / NK, j = t % NK;
    int idx; float s;
    if      (j <  6) { idx = 30 + j;        s = 1.0f; }   // p0
    else if (j < 12) { idx = 30 + (j - 6);  s = 1.5f; }   // p01
    else if (j < 25) { idx =  2 + (j - 12); s = 0.7f; }   // p12
    else if (j < 38) { idx =  2 + (j - 25); s = 0.9f; }   // p13
    else if (j < 51) { idx =  2 + (j - 38); s = 0.5f; }   // p11
    else if (j < 71) { idx = 48 + (j - 51); s = 1.0f; }   // p2
    else if (j < 76) { idx =  6 + (j - 71); s = 1.0f; }   // p3
    else             { idx = 48 + (j - 76); s = 1.3f; }   // p21
    const float scal = 364.0f / 512.0f;   // exact 0.7109375
    float lx = lm[b * 136 + idx * 2 + 0] * scal;
    float ly = lm[b * 136 + idx * 2 + 1] * scal;
    float kx, ky;
    if (s == 1.0f) { kx = lx; ky = ly; }
    else {
        float cx = lm[b * 136 + 30 * 2 + 0] * scal;
        float cy = lm[b * 136 + 30 * 2 + 1] * scal;
        kx = (lx - cx) * s + cx;
        ky = (ly - cy) * s + cy;
    }
    int ix = __float2int_rn(fminf(fmaxf(kx, 0.0f), (float)(SW - 1)));
    int iy = __float2int_rn(fminf(fmaxf(ky, 0.0f), (float)(SH - 1)));
    hm[iy * SW + ix] = 1.0f;   // all writers store 1.0 -> race-free
}

// ---------------- separable gaussian passes ----------------
__device__ __forceinline__ float gauss_w(int d) {
    return expf(-0.03125f * (float)(d * d));   // -0.5/sigma^2, sigma=4
}

__global__ void k_hconv(const float* __restrict__ in, float* __restrict__ out) {
    int t = blockIdx.x * blockDim.x + threadIdx.x;
    if (t >= HMN) return;
    int y = t / SW, x = t - y * SW;
    float acc = 0.0f, s1 = 0.0f;
    #pragma unroll
    for (int d = -RAD; d <= RAD; ++d) {
        float g = gauss_w(d);
        s1 += g;
        int xx = x + d;
        if (xx >= 0 && xx < SW) acc += g * in[y * SW + xx];
    }
    out[t] = acc / s1;
}

template <bool THRESH>
__global__ void k_vconv(const float* __restrict__ in, float* __restrict__ out) {
    int t = blockIdx.x * blockDim.x + threadIdx.x;
    if (t >= HMN) return;
    int y = t / SW, x = t - y * SW;
    float acc = 0.0f, s1 = 0.0f;
    #pragma unroll
    for (int d = -RAD; d <= RAD; ++d) {
        float g = gauss_w(d);
        s1 += g;
        int yy = y + d;
        if (yy >= 0 && yy < SH) acc += g * in[yy * SW + x];
    }
    float v = acc / s1;
    if (THRESH) v = (v > 1e-7f) ? 1.0f : v;
    out[t] = v;
}

// ---------------- bilinear upsample -> store (1 - mask) ----------------
__global__ void k_mask(const float* __restrict__ w3, float* __restrict__ om) {
    int t = blockIdx.x * blockDim.x + threadIdx.x;
    if (t >= OMN) return;
    int h = t >> 9, w = t & 511;
    float fy = ((float)h + 0.5f) * ((float)SH / (float)HH) - 0.5f;
    float fx = ((float)w + 0.5f) * ((float)SW / (float)WW) - 0.5f;
    fy = fminf(fmaxf(fy, 0.0f), (float)(SH - 1));
    fx = fminf(fmaxf(fx, 0.0f), (float)(SW - 1));
    int y0 = (int)fy, x0 = (int)fx;
    int y1 = min(y0 + 1, SH - 1), x1 = min(x0 + 1, SW - 1);
    float ty = fy - (float)y0, tx = fx - (float)x0;
    float v00 = w3[y0 * SW + x0], v01 = w3[y0 * SW + x1];
    float v10 = w3[y1 * SW + x0], v11 = w3[y1 * SW + x1];
    float v = (1.0f - ty) * ((1.0f - tx) * v00 + tx * v01)
            +         ty  * ((1.0f - tx) * v10 + tx * v11);
    om[t] = 1.0f - v;
}

// ---------------- final elementwise (memory-bound bulk) ----------------
__global__ void k_final(const float4* __restrict__ in, const float4* __restrict__ om,
                        float4* __restrict__ out, int n4) {
    int i = blockIdx.x * blockDim.x + threadIdx.x;
    if (i >= n4) return;
    float4 a = in[i];
    float4 m = om[i & (OMN / 4 - 1)];   // 65536 float4 per (b,c) plane, power of 2
    float4 r;
    r.x = a.x * m.x; r.y = a.y * m.y; r.z = a.z * m.z; r.w = a.w * m.w;
    out[i] = r;
}

extern "C" void kernel_launch(void* const* d_in, const int* in_sizes, int n_in,
                              void* d_out, int out_size, void* d_ws, size_t ws_size,
                              hipStream_t stream) {
    const float* face = (const float*)d_in[0];   // (32,3,512,512)
    const float* lm   = (const float*)d_in[1];   // (32,68,2)
    // d_in[2] (weight) unused: gaussian recomputed exactly (separable)

    float* ws  = (float*)d_ws;
    float* hm  = ws;             // 101920
    float* tmp = ws + HMN;       // 101920
    float* w2  = ws + 2 * HMN;   // 101920
    float* w3  = ws + 3 * HMN;   // 101920
    float* om  = ws + 4 * HMN;   // 262144 (16B-aligned: 4*HMN*4 = 1630720 bytes)

    // 1. zero heatmap
    k_zero<<<(HMN + 255) / 256, 256, 0, stream>>>(hm, HMN);
    // 2. scatter 32*96 keypoints
    k_scatter<<<(BB * NK + 255) / 256, 256, 0, stream>>>(lm, hm);
    // 3. blur #1 (separable) + threshold fused into vertical pass
    k_hconv<<<(HMN + 255) / 256, 256, 0, stream>>>(hm, tmp);
    k_vconv<true><<<(HMN + 255) / 256, 256, 0, stream>>>(tmp, w2);
    // 4. blur #2 (separable)
    k_hconv<<<(HMN + 255) / 256, 256, 0, stream>>>(w2, tmp);
    k_vconv<false><<<(HMN + 255) / 256, 256, 0, stream>>>(tmp, w3);
    // 5. bilinear resize -> (1 - mask), 512x512 once (batch-independent)
    k_mask<<<(OMN + 255) / 256, 256, 0, stream>>>(w3, om);
    // 6. out = (1-mask) * input, 201 MB of HBM traffic
    int n4 = out_size / 4;
    k_final<<<(n4 + 255) / 256, 256, 0, stream>>>(
        (const float4*)face, (const float4*)om, (float4*)d_out, n4);
}

// Round 3
// 61.329 us; speedup vs baseline: 1.0815x; 1.0815x over previous
//
#include <hip/hip_runtime.h>

#define BB   32
#define CH   3
#define HH   512
#define WW   512
#define SH   364
#define SW   280
#define RAD  15
#define NK   96
#define HMN  (SH*SW)          // 101920
#define OMN  (HH*WW)          // 262144

#define TS   32               // K1 heatmap tile
#define K1R  (TS + 2*RAD)     // 62
#define OH   48               // K2 output tile rows
#define OW   64               // K2 output tile cols
#define NRMX 36               // max w3 rows needed per K2 tile
#define NCMX 37               // max w3 cols needed per K2 tile

typedef float f4 __attribute__((ext_vector_type(4)));   // native vector for nontemporal builtins

__device__ __forceinline__ float gauss_w(int d) {
    return expf(-0.03125f * (float)(d * d));   // exp(-0.5/sigma^2 * d^2), sigma=4
}

// derived keypoint j (0..95) of batch b -> rounded clipped (ix, iy) in heatmap space
__device__ __forceinline__ void point_ij(const float* __restrict__ lm, int b, int j,
                                         int& ix, int& iy) {
    int idx; float s;
    if      (j <  6) { idx = 30 + j;        s = 1.0f; }   // p0
    else if (j < 12) { idx = 30 + (j - 6);  s = 1.5f; }   // p01
    else if (j < 25) { idx =  2 + (j - 12); s = 0.7f; }   // p12
    else if (j < 38) { idx =  2 + (j - 25); s = 0.9f; }   // p13
    else if (j < 51) { idx =  2 + (j - 38); s = 0.5f; }   // p11
    else if (j < 71) { idx = 48 + (j - 51); s = 1.0f; }   // p2
    else if (j < 76) { idx =  6 + (j - 71); s = 1.0f; }   // p3
    else             { idx = 48 + (j - 76); s = 1.3f; }   // p21
    const float scal = 364.0f / 512.0f;   // exact 0.7109375
    float lx = lm[b * 136 + idx * 2 + 0] * scal;
    float ly = lm[b * 136 + idx * 2 + 1] * scal;
    float kx, ky;
    if (s == 1.0f) { kx = lx; ky = ly; }
    else {
        float cx = lm[b * 136 + 30 * 2 + 0] * scal;
        float cy = lm[b * 136 + 30 * 2 + 1] * scal;
        kx = (lx - cx) * s + cx;
        ky = (ly - cy) * s + cy;
    }
    ix = __float2int_rn(fminf(fmaxf(kx, 0.0f), (float)(SW - 1)));
    iy = __float2int_rn(fminf(fmaxf(ky, 0.0f), (float)(SH - 1)));
}

// ---------------- K1: scatter-in-LDS + blur#1 + threshold -> w2 ----------------
__global__ __launch_bounds__(256) void k_blur1(const float* __restrict__ lm,
                                               float* __restrict__ w2) {
    __shared__ float hm[K1R][K1R];     // 62x62 heatmap region (with halo)
    __shared__ float tmp[K1R][TS];     // 62x32 after h-conv
    const int r0 = blockIdx.y * TS, c0 = blockIdx.x * TS;
    const int tid = threadIdx.x;

    for (int i = tid; i < K1R * K1R; i += 256) ((float*)hm)[i] = 0.0f;
    __syncthreads();

    // all 3072 derived points; set 1.0 where they land in this block's region
    for (int p = tid; p < BB * NK; p += 256) {
        int b = p / NK, j = p - b * NK;
        int ix, iy;
        point_ij(lm, b, j, ix, iy);
        int ly = iy - (r0 - RAD), lx = ix - (c0 - RAD);
        if (ly >= 0 && ly < K1R && lx >= 0 && lx < K1R) hm[ly][lx] = 1.0f;
    }
    __syncthreads();

    // horizontal pass (zero-padded via LDS zeros outside image)
    for (int i = tid; i < K1R * TS; i += 256) {
        int yy = i / TS, x = i - yy * TS;
        float acc = 0.0f, s1 = 0.0f;
        #pragma unroll
        for (int d = -RAD; d <= RAD; ++d) {
            float g = gauss_w(d);
            s1 += g;
            acc += g * hm[yy][x + RAD + d];
        }
        tmp[yy][x] = acc / s1;
    }
    __syncthreads();

    // vertical pass + threshold -> w2
    for (int i = tid; i < TS * TS; i += 256) {
        int y = i / TS, x = i - y * TS;
        int gy = r0 + y, gx = c0 + x;
        if (gy >= SH || gx >= SW) continue;
        float acc = 0.0f, s1 = 0.0f;
        #pragma unroll
        for (int d = -RAD; d <= RAD; ++d) {
            float g = gauss_w(d);
            s1 += g;
            acc += g * tmp[y + RAD + d][x];
        }
        float v = acc / s1;
        w2[gy * SW + gx] = (v > 1e-7f) ? 1.0f : v;
    }
}

// ------------- K2: blur#2 + bilinear resize + (1-mask) -> om (512x512) -------------
__global__ __launch_bounds__(256) void k_blur2_mask(const float* __restrict__ w2,
                                                    float* __restrict__ om) {
    __shared__ float w2r[NRMX + 2*RAD][NCMX + 2*RAD];   // 66x67 staged w2 region
    __shared__ float tmp[NRMX + 2*RAD][NCMX];           // 66x37 after h-conv
    __shared__ float w3r[NRMX][NCMX];                   // 36x37 final blurred region
    const int h0 = blockIdx.y * OH, w0 = blockIdx.x * OW;
    const int hl = min(h0 + OH - 1, HH - 1), wl = min(w0 + OW - 1, WW - 1);
    const int tid = threadIdx.x;
    const float sy = (float)SH / (float)HH;   // 0.7109375
    const float sx = (float)SW / (float)WW;   // 0.546875

    // w3 rows/cols this tile needs (monotone coord map, clamped)
    float fy0 = fmaxf(((float)h0 + 0.5f) * sy - 0.5f, 0.0f);
    float fyl = fminf(((float)hl + 0.5f) * sy - 0.5f, (float)(SH - 1));
    int rbase = (int)fy0;
    int rend  = min(SH - 1, (int)fyl + 1);
    int NR = rend - rbase + 1;                // <= 36
    float fx0 = fmaxf(((float)w0 + 0.5f) * sx - 0.5f, 0.0f);
    float fxl = fminf(((float)wl + 0.5f) * sx - 0.5f, (float)(SW - 1));
    int cbase = (int)fx0;
    int cend  = min(SW - 1, (int)fxl + 1);
    int NC = cend - cbase + 1;                // <= 37
    int SR = NR + 2 * RAD, SC = NC + 2 * RAD;

    // stage w2 region (zero-pad outside image)
    for (int i = tid; i < SR * SC; i += 256) {
        int y = i / SC, x = i - y * SC;
        int gy = rbase - RAD + y, gx = cbase - RAD + x;
        float v = 0.0f;
        if (gy >= 0 && gy < SH && gx >= 0 && gx < SW) v = w2[gy * SW + gx];
        w2r[y][x] = v;
    }
    __syncthreads();

    // horizontal pass
    for (int i = tid; i < SR * NC; i += 256) {
        int yy = i / NC, x = i - yy * NC;
        float acc = 0.0f, s1 = 0.0f;
        #pragma unroll
        for (int d = -RAD; d <= RAD; ++d) {
            float g = gauss_w(d);
            s1 += g;
            acc += g * w2r[yy][x + RAD + d];
        }
        tmp[yy][x] = acc / s1;
    }
    __syncthreads();

    // vertical pass
    for (int i = tid; i < NR * NC; i += 256) {
        int y = i / NC, x = i - y * NC;
        float acc = 0.0f, s1 = 0.0f;
        #pragma unroll
        for (int d = -RAD; d <= RAD; ++d) {
            float g = gauss_w(d);
            s1 += g;
            acc += g * tmp[y + RAD + d][x];
        }
        w3r[y][x] = acc / s1;
    }
    __syncthreads();

    // bilinear resize + (1 - v) epilogue
    for (int i = tid; i < OH * OW; i += 256) {
        int dh = i / OW, dw = i - dh * OW;
        int h = h0 + dh, w = w0 + dw;
        if (h >= HH || w >= WW) continue;
        float fy = fminf(fmaxf(((float)h + 0.5f) * sy - 0.5f, 0.0f), (float)(SH - 1));
        float fx = fminf(fmaxf(((float)w + 0.5f) * sx - 0.5f, 0.0f), (float)(SW - 1));
        int y0 = (int)fy, x0 = (int)fx;
        int y1 = min(y0 + 1, SH - 1), x1 = min(x0 + 1, SW - 1);
        float ty = fy - (float)y0, tx = fx - (float)x0;
        int ly0 = y0 - rbase, ly1 = y1 - rbase;
        int lx0 = x0 - cbase, lx1 = x1 - cbase;
        float v00 = w3r[ly0][lx0], v01 = w3r[ly0][lx1];
        float v10 = w3r[ly1][lx0], v11 = w3r[ly1][lx1];
        float v = (1.0f - ty) * ((1.0f - tx) * v00 + tx * v01)
                +         ty  * ((1.0f - tx) * v10 + tx * v11);
        om[h * WW + w] = 1.0f - v;
    }
}

// ---------------- K3: out = (1-mask) * input (201 MB streaming) ----------------
__global__ __launch_bounds__(256) void k_final(const f4* __restrict__ in,
                                               const f4* __restrict__ om,
                                               f4* __restrict__ out, int n4) {
    int i = blockIdx.x * blockDim.x + threadIdx.x;
    if (i >= n4) return;
    f4 a = __builtin_nontemporal_load(&in[i]);
    f4 m = om[i & (OMN / 4 - 1)];   // mask plane cached in L2
    f4 r = a * m;
    __builtin_nontemporal_store(r, &out[i]);
}

extern "C" void kernel_launch(void* const* d_in, const int* in_sizes, int n_in,
                              void* d_out, int out_size, void* d_ws, size_t ws_size,
                              hipStream_t stream) {
    const float* face = (const float*)d_in[0];   // (32,3,512,512)
    const float* lm   = (const float*)d_in[1];   // (32,68,2)
    // d_in[2] (weight) unused: gaussian recomputed exactly (separable)

    float* ws = (float*)d_ws;
    float* w2 = ws;            // 101920 floats
    float* om = ws + HMN;      // 262144 floats (offset 407680 B, 16B-aligned)

    // K1: scatter + blur#1 + threshold (9x12 tiles of 32x32)
    k_blur1<<<dim3((SW + TS - 1) / TS, (SH + TS - 1) / TS), 256, 0, stream>>>(lm, w2);
    // K2: blur#2 + bilinear + (1-mask) (8x11 output tiles of 64x48)
    k_blur2_mask<<<dim3(WW / OW, (HH + OH - 1) / OH), 256, 0, stream>>>(w2, om);
    // K3: streaming multiply
    int n4 = out_size / 4;
    k_final<<<(n4 + 255) / 256, 256, 0, stream>>>(
        (const f4*)face, (const f4*)om, (f4*)d_out, n4);
}

// Round 4
// 58.517 us; speedup vs baseline: 1.1335x; 1.0481x over previous
//
#include <hip/hip_runtime.h>

#define BB   32
#define HH   512
#define WW   512
#define SH   364
#define SW   280
#define RAD  15
#define NK   96
#define OMN  (HH*WW)          // 262144

#define OH   16               // output tile rows per block
#define OW   32               // output tile cols per block
#define NRM  13               // max w3 rows a tile needs
#define NCM  19               // max w3 cols a tile needs
#define WRM  (NRM + 2*RAD)    // 43 w2 rows (w3 + blur2 halo)
#define WCM  (NCM + 2*RAD)    // 49 w2 cols
#define HRM  (NRM + 4*RAD)    // 73 hm rows (+ blur1 halo)
#define HCM  (NCM + 4*RAD)    // 79 hm cols

typedef float f4 __attribute__((ext_vector_type(4)));

// derived keypoint j (0..95) of batch b -> rounded clipped (ix, iy) in heatmap space
__device__ __forceinline__ void point_ij(const float* __restrict__ lm, int b, int j,
                                         int& ix, int& iy) {
    int idx; float s;
    if      (j <  6) { idx = 30 + j;        s = 1.0f; }   // p0
    else if (j < 12) { idx = 30 + (j - 6);  s = 1.5f; }   // p01
    else if (j < 25) { idx =  2 + (j - 12); s = 0.7f; }   // p12
    else if (j < 38) { idx =  2 + (j - 25); s = 0.9f; }   // p13
    else if (j < 51) { idx =  2 + (j - 38); s = 0.5f; }   // p11
    else if (j < 71) { idx = 48 + (j - 51); s = 1.0f; }   // p2
    else if (j < 76) { idx =  6 + (j - 71); s = 1.0f; }   // p3
    else             { idx = 48 + (j - 76); s = 1.3f; }   // p21
    const float scal = 364.0f / 512.0f;   // exact 0.7109375
    float lx = lm[b * 136 + idx * 2 + 0] * scal;
    float ly = lm[b * 136 + idx * 2 + 1] * scal;
    float kx, ky;
    if (s == 1.0f) { kx = lx; ky = ly; }
    else {
        float cx = lm[b * 136 + 30 * 2 + 0] * scal;
        float cy = lm[b * 136 + 30 * 2 + 1] * scal;
        kx = (lx - cx) * s + cx;
        ky = (ly - cy) * s + cy;
    }
    ix = __float2int_rn(fminf(fmaxf(kx, 0.0f), (float)(SW - 1)));
    iy = __float2int_rn(fminf(fmaxf(ky, 0.0f), (float)(SH - 1)));
}

// ---- K_mask: whole mask pipeline per output tile, one kernel, 512 blocks ----
// scatter -> blur1(sep) -> threshold -> blur2(sep) -> bilinear -> (1-mask) -> om
__global__ __launch_bounds__(256) void k_mask(const float* __restrict__ lm,
                                              const float* __restrict__ wt,
                                              float* __restrict__ om) {
    __shared__ float gwl[31];
    __shared__ float hmS[HRM][HCM];   // 73x79 binary heatmap region
    __shared__ float t1 [HRM][WCM];   // 73x49 after blur1 h-pass
    __shared__ float w2S[WRM][WCM];   // 43x49 thresholded blur1
    __shared__ float t2 [WRM][NCM];   // 43x19 after blur2 h-pass
    __shared__ float w3S[NRM][NCM];   // 13x19 final blurred region

    const int tid = threadIdx.x;
    const int h0 = blockIdx.y * OH, w0 = blockIdx.x * OW;
    const float sy = (float)SH / (float)HH;   // 0.7109375
    const float sx = (float)SW / (float)WW;   // 0.546875

    // exact normalized 1D profile from the reference 2D kernel:
    // gn[j] = W[15][j] / sqrt(W[15][15])  =>  gn[i]*gn[j] == W[i][j] (1-2 ulp)
    if (tid < 31) gwl[tid] = wt[15 * 31 + tid] / sqrtf(wt[15 * 31 + 15]);

    // w3 rows/cols this tile needs (monotone coord map, clamped)
    const int hl = h0 + OH - 1, wl = w0 + OW - 1;
    float fy0 = fmaxf(((float)h0 + 0.5f) * sy - 0.5f, 0.0f);
    float fyl = fminf(((float)hl + 0.5f) * sy - 0.5f, (float)(SH - 1));
    int rbase = (int)fy0;
    int rend  = min(SH - 1, (int)fyl + 1);
    float fx0 = fmaxf(((float)w0 + 0.5f) * sx - 0.5f, 0.0f);
    float fxl = fminf(((float)wl + 0.5f) * sx - 0.5f, (float)(SW - 1));
    int cbase = (int)fx0;
    int cend  = min(SW - 1, (int)fxl + 1);
    int NR = rend - rbase + 1;          // <= 13
    int NC = cend - cbase + 1;          // <= 19
    int HR = NR + 4 * RAD, HC = NC + 4 * RAD;   // hm region actually consumed

    // zero heatmap region
    for (int i = tid; i < HRM * HCM; i += 256) ((float*)hmS)[i] = 0.0f;
    __syncthreads();

    // weights to registers (constant indices after unroll)
    float g[31];
    #pragma unroll
    for (int k = 0; k < 31; ++k) g[k] = gwl[k];

    // scatter all 3072 derived points landing in this block's hm region
    for (int p = tid; p < BB * NK; p += 256) {
        int b = p / NK, j = p - b * NK;
        int ix, iy;
        point_ij(lm, b, j, ix, iy);
        int ly = iy - (rbase - 2 * RAD), lx = ix - (cbase - 2 * RAD);
        if (ly >= 0 && ly < HR && lx >= 0 && lx < HC) hmS[ly][lx] = 1.0f;
    }
    __syncthreads();

    // blur1 horizontal: t1[y][x] ~ hm cols (x .. x+30)
    for (int i = tid; i < HRM * WCM; i += 256) {
        int y = i / WCM, x = i - y * WCM;
        float acc = 0.0f;
        #pragma unroll
        for (int d = 0; d < 31; ++d) acc += g[d] * hmS[y][x + d];
        t1[y][x] = acc;
    }
    __syncthreads();

    // blur1 vertical + threshold; zero outside image (blur2 zero-padding)
    for (int i = tid; i < WRM * WCM; i += 256) {
        int y = i / WCM, x = i - y * WCM;
        float acc = 0.0f;
        #pragma unroll
        for (int d = 0; d < 31; ++d) acc += g[d] * t1[y + d][x];
        float v = (acc > 1e-7f) ? 1.0f : acc;
        int gy = rbase - RAD + y, gx = cbase - RAD + x;
        w2S[y][x] = (gy >= 0 && gy < SH && gx >= 0 && gx < SW) ? v : 0.0f;
    }
    __syncthreads();

    // blur2 horizontal
    for (int i = tid; i < WRM * NCM; i += 256) {
        int y = i / NCM, x = i - y * NCM;
        float acc = 0.0f;
        #pragma unroll
        for (int d = 0; d < 31; ++d) acc += g[d] * w2S[y][x + d];
        t2[y][x] = acc;
    }
    __syncthreads();

    // blur2 vertical
    for (int i = tid; i < NRM * NCM; i += 256) {
        int y = i / NCM, x = i - y * NCM;
        float acc = 0.0f;
        #pragma unroll
        for (int d = 0; d < 31; ++d) acc += g[d] * t2[y + d][x];
        w3S[y][x] = acc;
    }
    __syncthreads();

    // bilinear resize + (1 - v) epilogue
    for (int i = tid; i < OH * OW; i += 256) {
        int dh = i / OW, dw = i - dh * OW;
        int h = h0 + dh, w = w0 + dw;
        float fy = fminf(fmaxf(((float)h + 0.5f) * sy - 0.5f, 0.0f), (float)(SH - 1));
        float fx = fminf(fmaxf(((float)w + 0.5f) * sx - 0.5f, 0.0f), (float)(SW - 1));
        int y0 = (int)fy, x0 = (int)fx;
        int y1 = min(y0 + 1, SH - 1), x1 = min(x0 + 1, SW - 1);
        float ty = fy - (float)y0, tx = fx - (float)x0;
        int ly0 = y0 - rbase, ly1 = y1 - rbase;
        int lx0 = x0 - cbase, lx1 = x1 - cbase;
        float v00 = w3S[ly0][lx0], v01 = w3S[ly0][lx1];
        float v10 = w3S[ly1][lx0], v11 = w3S[ly1][lx1];
        float v = (1.0f - ty) * ((1.0f - tx) * v00 + tx * v01)
                +         ty  * ((1.0f - tx) * v10 + tx * v11);
        om[h * WW + w] = 1.0f - v;
    }
}

// ---- K3: out = mask * input, grid-stride streaming, mask hoisted ----
__global__ __launch_bounds__(256) void k_final(const f4* __restrict__ in,
                                               const f4* __restrict__ om,
                                               f4* __restrict__ out, int n4) {
    const int i0 = blockIdx.x * 256 + threadIdx.x;
    // stride (2048*256 = 524288) is a multiple of the mask plane size in f4
    // (65536), so the mask element is loop-invariant per thread: load once.
    f4 m = om[i0 & (OMN / 4 - 1)];
    const int stride = gridDim.x * 256;
    for (int i = i0; i < n4; i += stride) {
        f4 a = __builtin_nontemporal_load(&in[i]);
        __builtin_nontemporal_store(a * m, &out[i]);
    }
}

extern "C" void kernel_launch(void* const* d_in, const int* in_sizes, int n_in,
                              void* d_out, int out_size, void* d_ws, size_t ws_size,
                              hipStream_t stream) {
    const float* face = (const float*)d_in[0];   // (32,3,512,512)
    const float* lm   = (const float*)d_in[1];   // (32,68,2)
    const float* wt   = (const float*)d_in[2];   // (1,1,31,31) gaussian, normalized

    float* om = (float*)d_ws;                    // 262144 floats (1 MB)

    // K_mask: 16x32 grid of 32x16 output tiles = 512 blocks (~2/CU)
    k_mask<<<dim3(WW / OW, HH / OH), 256, 0, stream>>>(lm, wt, om);
    // K3: streaming multiply, 2048 blocks grid-stride (stride % 65536 == 0)
    int n4 = out_size / 4;
    k_final<<<2048, 256, 0, stream>>>(
        (const f4*)face, (const f4*)om, (f4*)d_out, n4);
}

// Round 5
// 57.804 us; speedup vs baseline: 1.1474x; 1.0123x over previous
//
#include <hip/hip_runtime.h>

#define BB   32
#define HH   512
#define WW   512
#define SH   364
#define SW   280
#define RAD  15
#define NK   96
#define OMN  (HH*WW)          // 262144

#define OH   16               // output tile rows per block
#define OW   32               // output tile cols per block
#define NRM  13               // max w3 rows a tile needs
#define NCM  19               // max w3 cols a tile needs
#define WRM  (NRM + 2*RAD)    // 43 w2 rows (w3 + blur2 halo)
#define WCM  (NCM + 2*RAD)    // 49 w2 cols
#define HRM  (NRM + 4*RAD)    // 73 hm rows (+ blur1 halo)
#define HCM  (NCM + 4*RAD)    // 79 hm cols

typedef float f4 __attribute__((ext_vector_type(4)));

// derived keypoint j (0..95) of batch b -> rounded clipped (ix, iy) in heatmap space
__device__ __forceinline__ void point_ij(const float* __restrict__ lm, int b, int j,
                                         int& ix, int& iy) {
    int idx; float s;
    if      (j <  6) { idx = 30 + j;        s = 1.0f; }   // p0
    else if (j < 12) { idx = 30 + (j - 6);  s = 1.5f; }   // p01
    else if (j < 25) { idx =  2 + (j - 12); s = 0.7f; }   // p12
    else if (j < 38) { idx =  2 + (j - 25); s = 0.9f; }   // p13
    else if (j < 51) { idx =  2 + (j - 38); s = 0.5f; }   // p11
    else if (j < 71) { idx = 48 + (j - 51); s = 1.0f; }   // p2
    else if (j < 76) { idx =  6 + (j - 71); s = 1.0f; }   // p3
    else             { idx = 48 + (j - 76); s = 1.3f; }   // p21
    const float scal = 364.0f / 512.0f;   // exact 0.7109375
    float lx = lm[b * 136 + idx * 2 + 0] * scal;
    float ly = lm[b * 136 + idx * 2 + 1] * scal;
    float kx, ky;
    if (s == 1.0f) { kx = lx; ky = ly; }
    else {
        float cx = lm[b * 136 + 30 * 2 + 0] * scal;
        float cy = lm[b * 136 + 30 * 2 + 1] * scal;
        kx = (lx - cx) * s + cx;
        ky = (ly - cy) * s + cy;
    }
    ix = __float2int_rn(fminf(fmaxf(kx, 0.0f), (float)(SW - 1)));
    iy = __float2int_rn(fminf(fmaxf(ky, 0.0f), (float)(SH - 1)));
}

// ---- K_mask: whole mask pipeline per output tile, one kernel, 512 blocks ----
// scatter -> blur1(sep) -> threshold -> blur2(sep) -> bilinear -> (1-mask) -> om
__global__ __launch_bounds__(256) void k_mask(const float* __restrict__ lm,
                                              const float* __restrict__ wt,
                                              float* __restrict__ om) {
    __shared__ float gwl[31];
    __shared__ float hmS[HRM][HCM];   // 73x79 binary heatmap region
    __shared__ float t1 [HRM][WCM];   // 73x49 after blur1 h-pass
    __shared__ float w2S[WRM][WCM];   // 43x49 thresholded blur1
    __shared__ float t2 [WRM][NCM];   // 43x19 after blur2 h-pass
    __shared__ float w3S[NRM][NCM];   // 13x19 final blurred region

    const int tid = threadIdx.x;
    const int h0 = blockIdx.y * OH, w0 = blockIdx.x * OW;
    const float sy = (float)SH / (float)HH;   // 0.7109375
    const float sx = (float)SW / (float)WW;   // 0.546875

    // exact normalized 1D profile from the reference 2D kernel:
    // gn[j] = W[15][j] / sqrt(W[15][15])  =>  gn[i]*gn[j] == W[i][j] (1-2 ulp)
    if (tid < 31) gwl[tid] = wt[15 * 31 + tid] / sqrtf(wt[15 * 31 + 15]);

    // w3 rows/cols this tile needs (monotone coord map, clamped)
    const int hl = h0 + OH - 1, wl = w0 + OW - 1;
    float fy0 = fmaxf(((float)h0 + 0.5f) * sy - 0.5f, 0.0f);
    float fyl = fminf(((float)hl + 0.5f) * sy - 0.5f, (float)(SH - 1));
    int rbase = (int)fy0;
    int rend  = min(SH - 1, (int)fyl + 1);
    float fx0 = fmaxf(((float)w0 + 0.5f) * sx - 0.5f, 0.0f);
    float fxl = fminf(((float)wl + 0.5f) * sx - 0.5f, (float)(SW - 1));
    int cbase = (int)fx0;
    int cend  = min(SW - 1, (int)fxl + 1);
    int NR = rend - rbase + 1;          // <= 13
    int NC = cend - cbase + 1;          // <= 19
    int HR = NR + 4 * RAD, HC = NC + 4 * RAD;   // hm region actually consumed

    // zero heatmap region
    for (int i = tid; i < HRM * HCM; i += 256) ((float*)hmS)[i] = 0.0f;
    __syncthreads();

    // weights to registers (constant indices after unroll)
    float g[31];
    #pragma unroll
    for (int k = 0; k < 31; ++k) g[k] = gwl[k];

    // scatter all 3072 derived points landing in this block's hm region
    for (int p = tid; p < BB * NK; p += 256) {
        int b = p / NK, j = p - b * NK;
        int ix, iy;
        point_ij(lm, b, j, ix, iy);
        int ly = iy - (rbase - 2 * RAD), lx = ix - (cbase - 2 * RAD);
        if (ly >= 0 && ly < HR && lx >= 0 && lx < HC) hmS[ly][lx] = 1.0f;
    }
    __syncthreads();

    // blur1 horizontal: t1[y][x] ~ hm cols (x .. x+30)
    for (int i = tid; i < HRM * WCM; i += 256) {
        int y = i / WCM, x = i - y * WCM;
        float acc = 0.0f;
        #pragma unroll
        for (int d = 0; d < 31; ++d) acc += g[d] * hmS[y][x + d];
        t1[y][x] = acc;
    }
    __syncthreads();

    // blur1 vertical + threshold; zero outside image (blur2 zero-padding)
    for (int i = tid; i < WRM * WCM; i += 256) {
        int y = i / WCM, x = i - y * WCM;
        float acc = 0.0f;
        #pragma unroll
        for (int d = 0; d < 31; ++d) acc += g[d] * t1[y + d][x];
        float v = (acc > 1e-7f) ? 1.0f : acc;
        int gy = rbase - RAD + y, gx = cbase - RAD + x;
        w2S[y][x] = (gy >= 0 && gy < SH && gx >= 0 && gx < SW) ? v : 0.0f;
    }
    __syncthreads();

    // blur2 horizontal
    for (int i = tid; i < WRM * NCM; i += 256) {
        int y = i / NCM, x = i - y * NCM;
        float acc = 0.0f;
        #pragma unroll
        for (int d = 0; d < 31; ++d) acc += g[d] * w2S[y][x + d];
        t2[y][x] = acc;
    }
    __syncthreads();

    // blur2 vertical
    for (int i = tid; i < NRM * NCM; i += 256) {
        int y = i / NCM, x = i - y * NCM;
        float acc = 0.0f;
        #pragma unroll
        for (int d = 0; d < 31; ++d) acc += g[d] * t2[y + d][x];
        w3S[y][x] = acc;
    }
    __syncthreads();

    // bilinear resize + (1 - v) epilogue
    for (int i = tid; i < OH * OW; i += 256) {
        int dh = i / OW, dw = i - dh * OW;
        int h = h0 + dh, w = w0 + dw;
        float fy = fminf(fmaxf(((float)h + 0.5f) * sy - 0.5f, 0.0f), (float)(SH - 1));
        float fx = fminf(fmaxf(((float)w + 0.5f) * sx - 0.5f, 0.0f), (float)(SW - 1));
        int y0 = (int)fy, x0 = (int)fx;
        int y1 = min(y0 + 1, SH - 1), x1 = min(x0 + 1, SW - 1);
        float ty = fy - (float)y0, tx = fx - (float)x0;
        int ly0 = y0 - rbase, ly1 = y1 - rbase;
        int lx0 = x0 - cbase, lx1 = x1 - cbase;
        float v00 = w3S[ly0][lx0], v01 = w3S[ly0][lx1];
        float v10 = w3S[ly1][lx0], v11 = w3S[ly1][lx1];
        float v = (1.0f - ty) * ((1.0f - tx) * v00 + tx * v01)
                +         ty  * ((1.0f - tx) * v10 + tx * v11);
        om[h * WW + w] = 1.0f - v;
    }
}

// ---- K3: out = mask * input, grid-stride streaming, mask hoisted ----
__global__ __launch_bounds__(256) void k_final(const f4* __restrict__ in,
                                               const f4* __restrict__ om,
                                               f4* __restrict__ out, int n4) {
    const int i0 = blockIdx.x * 256 + threadIdx.x;
    // stride (2048*256 = 524288) is a multiple of the mask plane size in f4
    // (65536), so the mask element is loop-invariant per thread: load once.
    f4 m = om[i0 & (OMN / 4 - 1)];
    const int stride = gridDim.x * 256;
    for (int i = i0; i < n4; i += stride) {
        f4 a = __builtin_nontemporal_load(&in[i]);
        __builtin_nontemporal_store(a * m, &out[i]);
    }
}

extern "C" void kernel_launch(void* const* d_in, const int* in_sizes, int n_in,
                              void* d_out, int out_size, void* d_ws, size_t ws_size,
                              hipStream_t stream) {
    const float* face = (const float*)d_in[0];   // (32,3,512,512)
    const float* lm   = (const float*)d_in[1];   // (32,68,2)
    const float* wt   = (const float*)d_in[2];   // (1,1,31,31) gaussian, normalized

    float* om = (float*)d_ws;                    // 262144 floats (1 MB)

    // K_mask: 16x32 grid of 32x16 output tiles = 512 blocks (~2/CU)
    k_mask<<<dim3(WW / OW, HH / OH), 256, 0, stream>>>(lm, wt, om);
    // K3: streaming multiply, 2048 blocks grid-stride (stride % 65536 == 0)
    int n4 = out_size / 4;
    k_final<<<2048, 256, 0, stream>>>(
        (const f4*)face, (const f4*)om, (f4*)d_out, n4);
}

// Round 6
// 56.860 us; speedup vs baseline: 1.1665x; 1.0166x over previous
//
#include <hip/hip_runtime.h>

#define BB   32
#define HH   512
#define WW   512
#define SH   364
#define SW   280
#define RAD  15
#define NK   96
#define OMN  (HH*WW)          // 262144

#define OH   16               // output tile rows per block
#define OW   32               // output tile cols per block
#define NRM  13               // max w3 rows a tile needs
#define NCM  19               // max w3 cols a tile needs
#define WRM  (NRM + 2*RAD)    // 43 w2 rows (w3 + blur2 halo)
#define WCM  (NCM + 2*RAD)    // 49 w2 cols
#define HRM  (NRM + 4*RAD)    // 73 hm rows (+ blur1 halo)
#define HCM  (NCM + 4*RAD)    // 79 hm cols

typedef float f4 __attribute__((ext_vector_type(4)));

// derived keypoint j (0..95) of batch b -> rounded clipped (ix, iy) in heatmap space
__device__ __forceinline__ void point_ij(const float* __restrict__ lm, int b, int j,
                                         int& ix, int& iy) {
    int idx; float s;
    if      (j <  6) { idx = 30 + j;        s = 1.0f; }   // p0
    else if (j < 12) { idx = 30 + (j - 6);  s = 1.5f; }   // p01
    else if (j < 25) { idx =  2 + (j - 12); s = 0.7f; }   // p12
    else if (j < 38) { idx =  2 + (j - 25); s = 0.9f; }   // p13
    else if (j < 51) { idx =  2 + (j - 38); s = 0.5f; }   // p11
    else if (j < 71) { idx = 48 + (j - 51); s = 1.0f; }   // p2
    else if (j < 76) { idx =  6 + (j - 71); s = 1.0f; }   // p3
    else             { idx = 48 + (j - 76); s = 1.3f; }   // p21
    const float scal = 364.0f / 512.0f;   // exact 0.7109375
    float lx = lm[b * 136 + idx * 2 + 0] * scal;
    float ly = lm[b * 136 + idx * 2 + 1] * scal;
    float kx, ky;
    if (s == 1.0f) { kx = lx; ky = ly; }
    else {
        float cx = lm[b * 136 + 30 * 2 + 0] * scal;
        float cy = lm[b * 136 + 30 * 2 + 1] * scal;
        kx = (lx - cx) * s + cx;
        ky = (ly - cy) * s + cy;
    }
    ix = __float2int_rn(fminf(fmaxf(kx, 0.0f), (float)(SW - 1)));
    iy = __float2int_rn(fminf(fmaxf(ky, 0.0f), (float)(SH - 1)));
}

// ---- K_mask: whole mask pipeline per output tile, one kernel, 512 blocks ----
// scatter -> blur1(sep) -> threshold -> blur2(sep) -> bilinear -> (1-mask) -> om
__global__ __launch_bounds__(256) void k_mask(const float* __restrict__ lm,
                                              const float* __restrict__ wt,
                                              float* __restrict__ om) {
    __shared__ float gwl[31];
    __shared__ float hmS[HRM][HCM];   // 73x79 binary heatmap region
    __shared__ float t1 [HRM][WCM];   // 73x49 after blur1 h-pass
    __shared__ float w2S[WRM][WCM];   // 43x49 thresholded blur1
    __shared__ float t2 [WRM][NCM];   // 43x19 after blur2 h-pass
    __shared__ float w3S[NRM][NCM];   // 13x19 final blurred region

    const int tid = threadIdx.x;
    const int h0 = blockIdx.y * OH, w0 = blockIdx.x * OW;
    const float sy = (float)SH / (float)HH;   // 0.7109375
    const float sx = (float)SW / (float)WW;   // 0.546875

    // exact normalized 1D profile from the reference 2D kernel:
    // gn[j] = W[15][j] / sqrt(W[15][15])  =>  gn[i]*gn[j] == W[i][j] (1-2 ulp)
    if (tid < 31) gwl[tid] = wt[15 * 31 + tid] / sqrtf(wt[15 * 31 + 15]);

    // w3 rows/cols this tile needs (monotone coord map, clamped)
    const int hl = h0 + OH - 1, wl = w0 + OW - 1;
    float fy0 = fmaxf(((float)h0 + 0.5f) * sy - 0.5f, 0.0f);
    float fyl = fminf(((float)hl + 0.5f) * sy - 0.5f, (float)(SH - 1));
    int rbase = (int)fy0;
    int rend  = min(SH - 1, (int)fyl + 1);
    float fx0 = fmaxf(((float)w0 + 0.5f) * sx - 0.5f, 0.0f);
    float fxl = fminf(((float)wl + 0.5f) * sx - 0.5f, (float)(SW - 1));
    int cbase = (int)fx0;
    int cend  = min(SW - 1, (int)fxl + 1);
    int NR = rend - rbase + 1;          // <= 13
    int NC = cend - cbase + 1;          // <= 19
    int HR = NR + 4 * RAD, HC = NC + 4 * RAD;   // hm region actually consumed

    // zero heatmap region
    for (int i = tid; i < HRM * HCM; i += 256) ((float*)hmS)[i] = 0.0f;
    __syncthreads();

    // weights to registers (constant indices after unroll)
    float g[31];
    #pragma unroll
    for (int k = 0; k < 31; ++k) g[k] = gwl[k];

    // scatter all 3072 derived points landing in this block's hm region
    for (int p = tid; p < BB * NK; p += 256) {
        int b = p / NK, j = p - b * NK;
        int ix, iy;
        point_ij(lm, b, j, ix, iy);
        int ly = iy - (rbase - 2 * RAD), lx = ix - (cbase - 2 * RAD);
        if (ly >= 0 && ly < HR && lx >= 0 && lx < HC) hmS[ly][lx] = 1.0f;
    }
    __syncthreads();

    // blur1 horizontal: t1[y][x] ~ hm cols (x .. x+30)
    for (int i = tid; i < HRM * WCM; i += 256) {
        int y = i / WCM, x = i - y * WCM;
        float acc = 0.0f;
        #pragma unroll
        for (int d = 0; d < 31; ++d) acc += g[d] * hmS[y][x + d];
        t1[y][x] = acc;
    }
    __syncthreads();

    // blur1 vertical + threshold; zero outside image (blur2 zero-padding)
    for (int i = tid; i < WRM * WCM; i += 256) {
        int y = i / WCM, x = i - y * WCM;
        float acc = 0.0f;
        #pragma unroll
        for (int d = 0; d < 31; ++d) acc += g[d] * t1[y + d][x];
        float v = (acc > 1e-7f) ? 1.0f : acc;
        int gy = rbase - RAD + y, gx = cbase - RAD + x;
        w2S[y][x] = (gy >= 0 && gy < SH && gx >= 0 && gx < SW) ? v : 0.0f;
    }
    __syncthreads();

    // blur2 horizontal
    for (int i = tid; i < WRM * NCM; i += 256) {
        int y = i / NCM, x = i - y * NCM;
        float acc = 0.0f;
        #pragma unroll
        for (int d = 0; d < 31; ++d) acc += g[d] * w2S[y][x + d];
        t2[y][x] = acc;
    }
    __syncthreads();

    // blur2 vertical
    for (int i = tid; i < NRM * NCM; i += 256) {
        int y = i / NCM, x = i - y * NCM;
        float acc = 0.0f;
        #pragma unroll
        for (int d = 0; d < 31; ++d) acc += g[d] * t2[y + d][x];
        w3S[y][x] = acc;
    }
    __syncthreads();

    // bilinear resize + (1 - v) epilogue
    for (int i = tid; i < OH * OW; i += 256) {
        int dh = i / OW, dw = i - dh * OW;
        int h = h0 + dh, w = w0 + dw;
        float fy = fminf(fmaxf(((float)h + 0.5f) * sy - 0.5f, 0.0f), (float)(SH - 1));
        float fx = fminf(fmaxf(((float)w + 0.5f) * sx - 0.5f, 0.0f), (float)(SW - 1));
        int y0 = (int)fy, x0 = (int)fx;
        int y1 = min(y0 + 1, SH - 1), x1 = min(x0 + 1, SW - 1);
        float ty = fy - (float)y0, tx = fx - (float)x0;
        int ly0 = y0 - rbase, ly1 = y1 - rbase;
        int lx0 = x0 - cbase, lx1 = x1 - cbase;
        float v00 = w3S[ly0][lx0], v01 = w3S[ly0][lx1];
        float v10 = w3S[ly1][lx0], v11 = w3S[ly1][lx1];
        float v = (1.0f - ty) * ((1.0f - tx) * v00 + tx * v01)
                +         ty  * ((1.0f - tx) * v10 + tx * v11);
        om[h * WW + w] = 1.0f - v;
    }
}

// ---- K3: out = mask * input — PLAIN loads/stores (match m13 copy µbench),
//      grid-stride, hoisted mask, 2-deep manual unroll for MLP ----
__global__ __launch_bounds__(256) void k_final(const f4* __restrict__ in,
                                               const f4* __restrict__ om,
                                               f4* __restrict__ out, int n4) {
    const int i0 = blockIdx.x * 256 + threadIdx.x;
    // stride (2048*256 = 524288) is a multiple of the mask plane size in f4
    // (65536), so the mask element is loop-invariant per thread: load once.
    const f4 m = om[i0 & (OMN / 4 - 1)];
    const int stride = gridDim.x * 256;
    int i = i0;
    // n4 = 6291456 = 12 * 524288: exactly 6 unrolled pairs, no tail
    for (; i + stride < n4; i += 2 * stride) {
        f4 a0 = in[i];
        f4 a1 = in[i + stride];
        out[i]          = a0 * m;
        out[i + stride] = a1 * m;
    }
    if (i < n4) out[i] = in[i] * m;
}

extern "C" void kernel_launch(void* const* d_in, const int* in_sizes, int n_in,
                              void* d_out, int out_size, void* d_ws, size_t ws_size,
                              hipStream_t stream) {
    const float* face = (const float*)d_in[0];   // (32,3,512,512)
    const float* lm   = (const float*)d_in[1];   // (32,68,2)
    const float* wt   = (const float*)d_in[2];   // (1,1,31,31) gaussian, normalized

    float* om = (float*)d_ws;                    // 262144 floats (1 MB)

    // K_mask: 16x32 grid of 32x16 output tiles = 512 blocks (~2/CU)
    k_mask<<<dim3(WW / OW, HH / OH), 256, 0, stream>>>(lm, wt, om);
    // K3: streaming multiply, 2048 blocks grid-stride (stride % 65536 == 0)
    int n4 = out_size / 4;
    k_final<<<2048, 256, 0, stream>>>(
        (const f4*)face, (const f4*)om, (f4*)d_out, n4);
}

// Round 7
// 54.966 us; speedup vs baseline: 1.2067x; 1.0344x over previous
//
#include <hip/hip_runtime.h>

#define BB   32
#define HH   512
#define WW   512
#define SH   364
#define SW   280
#define RAD  15
#define NK   96
#define OMN  (HH*WW)          // 262144

#define OH   16               // output tile rows per block
#define OW   32               // output tile cols per block
#define NRM  13               // max w3 rows a tile needs
#define NCM  19               // max w3 cols a tile needs
#define WRM  (NRM + 2*RAD)    // 43 w2 rows (w3 + blur2 halo)
#define WCM  (NCM + 2*RAD)    // 49 w2 cols
#define HRM  (NRM + 4*RAD)    // 73 hm rows (+ blur1 halo)
#define HCM  (NCM + 4*RAD)    // 79 hm cols

typedef float f4 __attribute__((ext_vector_type(4)));

// derived keypoint j (0..95) of batch b -> rounded clipped (ix, iy) in heatmap space
__device__ __forceinline__ void point_ij(const float* __restrict__ lm, int b, int j,
                                         int& ix, int& iy) {
    int idx; float s;
    if      (j <  6) { idx = 30 + j;        s = 1.0f; }   // p0
    else if (j < 12) { idx = 30 + (j - 6);  s = 1.5f; }   // p01
    else if (j < 25) { idx =  2 + (j - 12); s = 0.7f; }   // p12
    else if (j < 38) { idx =  2 + (j - 25); s = 0.9f; }   // p13
    else if (j < 51) { idx =  2 + (j - 38); s = 0.5f; }   // p11
    else if (j < 71) { idx = 48 + (j - 51); s = 1.0f; }   // p2
    else if (j < 76) { idx =  6 + (j - 71); s = 1.0f; }   // p3
    else             { idx = 48 + (j - 76); s = 1.3f; }   // p21
    const float scal = 364.0f / 512.0f;   // exact 0.7109375
    float lx = lm[b * 136 + idx * 2 + 0] * scal;
    float ly = lm[b * 136 + idx * 2 + 1] * scal;
    float kx, ky;
    if (s == 1.0f) { kx = lx; ky = ly; }
    else {
        float cx = lm[b * 136 + 30 * 2 + 0] * scal;
        float cy = lm[b * 136 + 30 * 2 + 1] * scal;
        kx = (lx - cx) * s + cx;
        ky = (ly - cy) * s + cy;
    }
    ix = __float2int_rn(fminf(fmaxf(kx, 0.0f), (float)(SW - 1)));
    iy = __float2int_rn(fminf(fmaxf(ky, 0.0f), (float)(SH - 1)));
}

// ---- K_mask: whole mask pipeline per output tile, one kernel, 512 blocks ----
// scatter -> blur1(sep) -> threshold -> blur2(sep) -> bilinear -> (1-mask) -> om
__global__ __launch_bounds__(256) void k_mask(const float* __restrict__ lm,
                                              const float* __restrict__ wt,
                                              float* __restrict__ om) {
    __shared__ float gwl[31];
    __shared__ float hmS[HRM][HCM];   // 73x79 binary heatmap region
    __shared__ float t1 [HRM][WCM];   // 73x49 after blur1 h-pass
    __shared__ float w2S[WRM][WCM];   // 43x49 thresholded blur1
    __shared__ float t2 [WRM][NCM];   // 43x19 after blur2 h-pass
    __shared__ float w3S[NRM][NCM];   // 13x19 final blurred region

    const int tid = threadIdx.x;
    const int h0 = blockIdx.y * OH, w0 = blockIdx.x * OW;
    const float sy = (float)SH / (float)HH;   // 0.7109375
    const float sx = (float)SW / (float)WW;   // 0.546875

    // exact normalized 1D profile from the reference 2D kernel:
    // gn[j] = W[15][j] / sqrt(W[15][15])  =>  gn[i]*gn[j] == W[i][j] (1-2 ulp)
    if (tid < 31) gwl[tid] = wt[15 * 31 + tid] / sqrtf(wt[15 * 31 + 15]);

    // w3 rows/cols this tile needs (monotone coord map, clamped)
    const int hl = h0 + OH - 1, wl = w0 + OW - 1;
    float fy0 = fmaxf(((float)h0 + 0.5f) * sy - 0.5f, 0.0f);
    float fyl = fminf(((float)hl + 0.5f) * sy - 0.5f, (float)(SH - 1));
    int rbase = (int)fy0;
    int rend  = min(SH - 1, (int)fyl + 1);
    float fx0 = fmaxf(((float)w0 + 0.5f) * sx - 0.5f, 0.0f);
    float fxl = fminf(((float)wl + 0.5f) * sx - 0.5f, (float)(SW - 1));
    int cbase = (int)fx0;
    int cend  = min(SW - 1, (int)fxl + 1);
    int NR = rend - rbase + 1;          // <= 13
    int NC = cend - cbase + 1;          // <= 19
    int HR = NR + 4 * RAD, HC = NC + 4 * RAD;   // hm region actually consumed

    // zero heatmap region
    for (int i = tid; i < HRM * HCM; i += 256) ((float*)hmS)[i] = 0.0f;
    __syncthreads();

    // weights to registers (constant indices after unroll)
    float g[31];
    #pragma unroll
    for (int k = 0; k < 31; ++k) g[k] = gwl[k];

    // scatter all 3072 derived points landing in this block's hm region
    for (int p = tid; p < BB * NK; p += 256) {
        int b = p / NK, j = p - b * NK;
        int ix, iy;
        point_ij(lm, b, j, ix, iy);
        int ly = iy - (rbase - 2 * RAD), lx = ix - (cbase - 2 * RAD);
        if (ly >= 0 && ly < HR && lx >= 0 && lx < HC) hmS[ly][lx] = 1.0f;
    }
    __syncthreads();

    // blur1 horizontal: t1[y][x] ~ hm cols (x .. x+30)
    for (int i = tid; i < HRM * WCM; i += 256) {
        int y = i / WCM, x = i - y * WCM;
        float acc = 0.0f;
        #pragma unroll
        for (int d = 0; d < 31; ++d) acc += g[d] * hmS[y][x + d];
        t1[y][x] = acc;
    }
    __syncthreads();

    // blur1 vertical + threshold; zero outside image (blur2 zero-padding)
    for (int i = tid; i < WRM * WCM; i += 256) {
        int y = i / WCM, x = i - y * WCM;
        float acc = 0.0f;
        #pragma unroll
        for (int d = 0; d < 31; ++d) acc += g[d] * t1[y + d][x];
        float v = (acc > 1e-7f) ? 1.0f : acc;
        int gy = rbase - RAD + y, gx = cbase - RAD + x;
        w2S[y][x] = (gy >= 0 && gy < SH && gx >= 0 && gx < SW) ? v : 0.0f;
    }
    __syncthreads();

    // blur2 horizontal
    for (int i = tid; i < WRM * NCM; i += 256) {
        int y = i / NCM, x = i - y * NCM;
        float acc = 0.0f;
        #pragma unroll
        for (int d = 0; d < 31; ++d) acc += g[d] * w2S[y][x + d];
        t2[y][x] = acc;
    }
    __syncthreads();

    // blur2 vertical
    for (int i = tid; i < NRM * NCM; i += 256) {
        int y = i / NCM, x = i - y * NCM;
        float acc = 0.0f;
        #pragma unroll
        for (int d = 0; d < 31; ++d) acc += g[d] * t2[y + d][x];
        w3S[y][x] = acc;
    }
    __syncthreads();

    // bilinear resize + (1 - v) epilogue
    for (int i = tid; i < OH * OW; i += 256) {
        int dh = i / OW, dw = i - dh * OW;
        int h = h0 + dh, w = w0 + dw;
        float fy = fminf(fmaxf(((float)h + 0.5f) * sy - 0.5f, 0.0f), (float)(SH - 1));
        float fx = fminf(fmaxf(((float)w + 0.5f) * sx - 0.5f, 0.0f), (float)(SW - 1));
        int y0 = (int)fy, x0 = (int)fx;
        int y1 = min(y0 + 1, SH - 1), x1 = min(x0 + 1, SW - 1);
        float ty = fy - (float)y0, tx = fx - (float)x0;
        int ly0 = y0 - rbase, ly1 = y1 - rbase;
        int lx0 = x0 - cbase, lx1 = x1 - cbase;
        float v00 = w3S[ly0][lx0], v01 = w3S[ly0][lx1];
        float v10 = w3S[ly1][lx0], v11 = w3S[ly1][lx1];
        float v = (1.0f - ty) * ((1.0f - tx) * v00 + tx * v01)
                +         ty  * ((1.0f - tx) * v10 + tx * v11);
        om[h * WW + w] = 1.0f - v;
    }
}

// ---- K3: µbench-replica streaming multiply ----
// Flat one-shot grid: each thread handles 4 f4 at stride 256 (block covers
// 1024 contiguous f4 = 16 KB; every wave-instruction is a contiguous 1 KiB
// segment). All 8 loads issued before any store; no loop, no tail, no waits
// between iterations. n4 = 6291456 = 6144 blocks * 1024 exactly.
__global__ __launch_bounds__(256) void k_final(const f4* __restrict__ in,
                                               const f4* __restrict__ om,
                                               f4* __restrict__ out) {
    const int base = blockIdx.x * 1024 + threadIdx.x;
    f4 a0 = in[base];
    f4 a1 = in[base + 256];
    f4 a2 = in[base + 512];
    f4 a3 = in[base + 768];
    f4 m0 = om[(base)       & (OMN / 4 - 1)];
    f4 m1 = om[(base + 256) & (OMN / 4 - 1)];
    f4 m2 = om[(base + 512) & (OMN / 4 - 1)];
    f4 m3 = om[(base + 768) & (OMN / 4 - 1)];
    out[base]       = a0 * m0;
    out[base + 256] = a1 * m1;
    out[base + 512] = a2 * m2;
    out[base + 768] = a3 * m3;
}

extern "C" void kernel_launch(void* const* d_in, const int* in_sizes, int n_in,
                              void* d_out, int out_size, void* d_ws, size_t ws_size,
                              hipStream_t stream) {
    const float* face = (const float*)d_in[0];   // (32,3,512,512)
    const float* lm   = (const float*)d_in[1];   // (32,68,2)
    const float* wt   = (const float*)d_in[2];   // (1,1,31,31) gaussian, normalized

    float* om = (float*)d_ws;                    // 262144 floats (1 MB)

    // K_mask: 16x32 grid of 32x16 output tiles = 512 blocks (~2/CU)
    k_mask<<<dim3(WW / OW, HH / OH), 256, 0, stream>>>(lm, wt, om);
    // K3: flat streaming multiply, 6144 blocks, 4 f4/thread
    int n4 = out_size / 4;           // 6291456
    int nblk = n4 / 1024;            // 6144
    k_final<<<nblk, 256, 0, stream>>>(
        (const f4*)face, (const f4*)om, (f4*)d_out);
}